// Round 3
// baseline (68.678 us; speedup 1.0000x reference)
//
#include <hip/hip_runtime.h>
#include <math.h>

#define HH 1024
#define WW 1024
#define TW 32                    // tile width  (j)
#define TH 8                     // tile height (i)
#define NTX (WW / TW)            // 32
#define NTY (HH / TH)            // 128
#define NT  (NTX * NTY)          // 4096 tiles
#define THREADS 256              // 1 pixel per thread
#define MAXG 512                 // >= N (500)

// Fused: per-block derive + cull + LDS-stage + raster. Inputs are ~14 KB
// total -> fully L2/L3 resident; redundant per-block derivation (~5
// transcendentals / gaussian / block) is cheaper than a second dispatch.
// pixel weight = 2^(-(u'^2+v'^2)),  u' = s*(i-j)+As,  v' = s*(i+j)+Bsn

__global__ __launch_bounds__(THREADS) void gauss_fused(
    const float* __restrict__ mean, const float* __restrict__ depth,
    const float* __restrict__ radii, const float* __restrict__ color,
    float* __restrict__ out, int n) {
  __shared__ int s_count;
  __shared__ int s_flag;               // any survivor with w1/w2 != 0?
  __shared__ float4 s_pa[MAXG];        // {s, As, Bsn, w0}
  __shared__ float2 s_pb[MAXG];        // {w1, w2}

  // scatter-swizzle: spread spatially-adjacent (equally-loaded) tiles
  // across CUs/XCDs for load balance. 1597 is odd -> bijection mod 4096.
  const int tile = (blockIdx.x * 1597) & (NT - 1);
  const int j0 = (tile & (NTX - 1)) * TW;
  const int i0 = (tile >> 5) * TH;     // NTX == 32

  if (threadIdx.x == 0) { s_count = 0; s_flag = 0; }
  __syncthreads();

  const float LOG2E = 1.4426950408889634f;
  const float TWO_PI = 6.283185307179586f;

  // ---- derive + cull + stage ----
  for (int g = threadIdx.x; g < n; g += THREADS) {
    float m0 = mean[2 * g + 0];
    float m1 = mean[2 * g + 1];
    float d  = depth[g];
    float r  = radii[g];
    float c0 = color[3 * g + 0];
    float c1 = color[3 * g + 1];
    float c2 = color[3 * g + 2];

    float q = 0.5f * LOG2E * __expf(-2.0f * r);  // scaled inv variance
    float s = sqrtf(q);
    float As  = (m1 - m0) * s;
    float Bsn = -(m0 + m1) * s;
    float norm = d * __frcp_rn(TWO_PI * __expf(r));
    float w0 = c0 * norm, w1 = c1 * norm, w2 = c2 * norm;
    float wmax = fmaxf(fabsf(w0), fmaxf(fabsf(w1), fabsf(w2)));
    // keep where wmax * 2^(-d2') >= 1e-5  ->  d2' <= log2(wmax*1e5)
    float R2s = __log2f(wmax * 1e5f);            // -inf if wmax==0

    float ul = fmaf(s, (float)(i0 - (j0 + TW - 1)), As);
    float uh = fmaf(s, (float)(i0 + TH - 1 - j0), As);
    float vl = fmaf(s, (float)(i0 + j0), Bsn);
    float vh = fmaf(s, (float)(i0 + TH - 1 + j0 + TW - 1), Bsn);
    float du = fmaxf(0.0f, fmaxf(ul, -uh));
    float dv = fmaxf(0.0f, fmaxf(vl, -vh));
    if (fmaf(du, du, dv * dv) <= R2s) {
      int idx = atomicAdd(&s_count, 1);
      if (idx < MAXG) {
        s_pa[idx] = make_float4(s, As, Bsn, w0);
        s_pb[idx] = make_float2(w1, w2);
        if (w1 != 0.0f || w2 != 0.0f) s_flag = 1;
      }
    }
  }
  __syncthreads();
  int cnt = s_count;
  if (cnt > MAXG) cnt = MAXG;
  const int rgb = s_flag;

  // ---- one pixel per thread ----
  const int jj = threadIdx.x & (TW - 1);
  const int ii = threadIdx.x >> 5;     // TW == 32
  const int i_glob = i0 + ii;
  const int j_glob = j0 + jj;
  const float t1 = (float)(i_glob - j_glob);
  const float t2 = (float)(i_glob + j_glob);

  float a0 = 0.0f, a1 = 0.0f, a2 = 0.0f;

  if (!rgb) {
    // single-channel fast path (covers the pure-red dataset; general-safe)
#pragma unroll 4
    for (int k = 0; k < cnt; ++k) {
      float4 pa = s_pa[k];
      float u = fmaf(t1, pa.x, pa.y);
      float v = fmaf(t2, pa.x, pa.z);
      float t = fmaf(v, v, u * u);
      float e = __builtin_amdgcn_exp2f(-t);
      a0 = fmaf(pa.w, e, a0);
    }
  } else {
#pragma unroll 4
    for (int k = 0; k < cnt; ++k) {
      float4 pa = s_pa[k];
      float2 pb = s_pb[k];
      float u = fmaf(t1, pa.x, pa.y);
      float v = fmaf(t2, pa.x, pa.z);
      float t = fmaf(v, v, u * u);
      float e = __builtin_amdgcn_exp2f(-t);
      a0 = fmaf(pa.w, e, a0);
      a1 = fmaf(pb.x, e, a1);
      a2 = fmaf(pb.y, e, a2);
    }
  }

  const int base = i_glob * WW + j_glob;
  out[0 * (HH * WW) + base] = a0;
  out[1 * (HH * WW) + base] = a1;
  out[2 * (HH * WW) + base] = a2;
}

extern "C" void kernel_launch(void* const* d_in, const int* in_sizes, int n_in,
                              void* d_out, int out_size, void* d_ws, size_t ws_size,
                              hipStream_t stream) {
  const float* mean  = (const float*)d_in[0];
  const float* depth = (const float*)d_in[1];
  const float* radii = (const float*)d_in[2];
  const float* color = (const float*)d_in[3];
  float* out = (float*)d_out;
  int n = in_sizes[1];            // depth: one element per gaussian

  gauss_fused<<<dim3(NT), THREADS, 0, stream>>>(mean, depth, radii, color,
                                                out, n);
}